// Round 9
// baseline (221.675 us; speedup 1.0000x reference)
//
#include <hip/hip_runtime.h>

// GCN 2-layer, N=200000, E=3200000.
// R20c: third submission of sort-eliminated pipeline (two prior attempts hit
// "container failed twice" — infra signature: no pytest output, no counters;
// all kernel patterns herein have individually passed in R16/R17/R18/R19).
// SORT ELIMINATED: k_build's counting sort + 13MB writeback existed only to
// enable pull-mode agg. Buckets (512 nodes) fit block LDS accumulators, so
// agg is EDGE-PARALLEL per bucket-block on the unsorted slab (R17 proved
// LDS float atomics correct and cheap; its slowness was cooperative
// lockstep, absent here — independent self-balancing launches).
// Pipeline: memset + k_bin -> k_deg -> k_agg1 -> k_agg2.

#define BSE   512     // bin block size
#define CH    16384   // edges per bin block (LDS stage = 64KB)
#define NBW   512     // nodes per bucket
#define SH    9       // log2(NBW)
#define NB    391     // buckets = ceil(200000/512)
#define FCAP  10752   // slab capacity (valid mean 8184 + pad mean ~1470, +10 sigma)
#define BSB   512     // deg/agg block size
#define NOEDGE 0xFFFFFFFFu

typedef unsigned u32x4 __attribute__((ext_vector_type(4)));

// P1: bin. count -> scan+reserve -> LDS counting sort -> linear coalesced
// write-out -> sentinel-fill pad. (unchanged from R16, proven)
__global__ void k_bin(const int* __restrict__ src, const int* __restrict__ dst,
                      int E, unsigned* __restrict__ gcur,
                      unsigned* __restrict__ epack) {
    __shared__ unsigned stage[CH];       // 64KB: bucket-sorted chunk
    __shared__ unsigned cnt[NB];
    __shared__ unsigned ofs[NB + 1];     // exclusive scan of cnt
    __shared__ unsigned curp[NB];        // LDS scatter cursor
    __shared__ unsigned gbase[NB];       // global slab base per bucket
    __shared__ unsigned wsum[BSE / 64];
    const int b = blockIdx.x, t = threadIdx.x;
    for (int i = t; i < NB; i += BSE) cnt[i] = 0;
    __syncthreads();
    const int lo = b * CH, hi = min(E, lo + CH);
    const int n = hi - lo;
    const int aligned = n & ~3;
    // pass 1: count per bucket
    for (int i = 4 * t; i + 3 < n; i += 4 * BSE) {
        int4 d4 = *(const int4*)(dst + lo + i);
        atomicAdd(&cnt[((unsigned)d4.x) >> SH], 1u);
        atomicAdd(&cnt[((unsigned)d4.y) >> SH], 1u);
        atomicAdd(&cnt[((unsigned)d4.z) >> SH], 1u);
        atomicAdd(&cnt[((unsigned)d4.w) >> SH], 1u);
    }
    for (int i = aligned + t; i < n; i += BSE)
        atomicAdd(&cnt[((unsigned)dst[lo + i]) >> SH], 1u);
    __syncthreads();
    // block scan of bucket counts (shuffle scan, 512 lanes covers NB=391)
    const unsigned c = (t < NB) ? cnt[t] : 0u;
    unsigned v = c;
    #pragma unroll
    for (int off = 1; off < 64; off <<= 1) {
        unsigned u = __shfl_up(v, off);
        if ((t & 63) >= off) v += u;
    }
    if ((t & 63) == 63) wsum[t >> 6] = v;
    __syncthreads();
    if (t < BSE / 64) {
        unsigned w = wsum[t];
        #pragma unroll
        for (int off = 1; off < BSE / 64; off <<= 1) {
            unsigned u = __shfl_up(w, off);
            if (t >= off) w += u;
        }
        wsum[t] = w;
    }
    __syncthreads();
    const unsigned incl = v + ((t >> 6) ? wsum[(t >> 6) - 1] : 0u);
    const unsigned excl = incl - c;
    if (t < NB) {
        ofs[t] = excl;
        curp[t] = excl;
        unsigned pad = (c + 15u) & ~15u;             // 64B-aligned reservation
        unsigned o = pad ? atomicAdd(&gcur[t], pad) : 0u;
        gbase[t] = (unsigned)t * FCAP + o;
    }
    if (t == NB - 1) ofs[NB] = incl;                 // = n
    __syncthreads();
    // pass 2: counting-sort edges into LDS
    for (int i = 4 * t; i + 3 < n; i += 4 * BSE) {
        int4 d4 = *(const int4*)(dst + lo + i);
        int4 s4 = *(const int4*)(src + lo + i);
        unsigned k0 = ((unsigned)d4.x) >> SH, k1 = ((unsigned)d4.y) >> SH;
        unsigned k2 = ((unsigned)d4.z) >> SH, k3 = ((unsigned)d4.w) >> SH;
        unsigned p0 = atomicAdd(&curp[k0], 1u);
        unsigned p1 = atomicAdd(&curp[k1], 1u);
        unsigned p2 = atomicAdd(&curp[k2], 1u);
        unsigned p3 = atomicAdd(&curp[k3], 1u);
        stage[p0] = ((unsigned)s4.x << SH) | (((unsigned)d4.x) & (NBW - 1u));
        stage[p1] = ((unsigned)s4.y << SH) | (((unsigned)d4.y) & (NBW - 1u));
        stage[p2] = ((unsigned)s4.z << SH) | (((unsigned)d4.z) & (NBW - 1u));
        stage[p3] = ((unsigned)s4.w << SH) | (((unsigned)d4.w) & (NBW - 1u));
    }
    for (int i = aligned + t; i < n; i += BSE) {
        unsigned d = (unsigned)dst[lo + i];
        unsigned k = d >> SH;
        unsigned pos = atomicAdd(&curp[k], 1u);
        stage[pos] = ((unsigned)src[lo + i] << SH) | (d & (NBW - 1u));
    }
    __syncthreads();
    // pass 3: linear write-out (bucket by binary search over scanned offsets)
    for (int p0 = 4 * t; p0 < n; p0 += 4 * BSE) {
        unsigned k = 0;                              // largest k: ofs[k] <= p0
        #pragma unroll
        for (unsigned s = 256; s; s >>= 1) {
            unsigned cand = k + s;
            if (cand <= NB && ofs[cand] <= (unsigned)p0) k = cand;
        }
        #pragma unroll
        for (int j = 0; j < 4; ++j) {
            int p = p0 + j;
            if (p >= n) break;
            while (ofs[k + 1] <= (unsigned)p) ++k;   // rare boundary advance
            unsigned addr = gbase[k] + ((unsigned)p - ofs[k]);
            if (addr < (k + 1u) * FCAP) epack[addr] = stage[p];
        }
    }
    // sentinel-fill the pad of each cell (disjoint regions, no sync needed)
    for (int i = t; i < NB; i += BSE) {
        unsigned s = gbase[i] + cnt[i];
        unsigned e = gbase[i] + ((cnt[i] + 15u) & ~15u);
        unsigned kend = ((unsigned)i + 1u) * FCAP;
        if (e > kend) e = kend;
        for (unsigned p = s; p < e; ++p) epack[p] = NOEDGE;
    }
}

// P2: per bucket — read slab once (coalesced), count degrees in LDS, emit
// di and x_scaled. No scan, no sort, no writeback.
__global__ __launch_bounds__(BSB)
void k_deg(const unsigned* __restrict__ epack, const unsigned* __restrict__ gcur,
           const float* __restrict__ x,
           float* __restrict__ di_arr, float* __restrict__ x_scaled, int N) {
    __shared__ unsigned cnt[NBW];
    const int b = blockIdx.x, t = threadIdx.x;
    const unsigned base = (unsigned)b * FCAP;
    const int len4 = min((int)gcur[b], FCAP) >> 2;   // len multiple of 16
    cnt[t] = 0;
    __syncthreads();
    const u32x4* ep4 = (const u32x4*)(epack + base);
    for (int i4 = t; i4 < len4; i4 += BSB) {
        u32x4 q = ep4[i4];
        #pragma unroll
        for (int e = 0; e < 4; ++e) {
            unsigned p = q[e];
            if (p != NOEDGE) atomicAdd(&cnt[p & (NBW - 1u)], 1u);
        }
    }
    __syncthreads();
    const int node = b * NBW + t;
    if (node < N) {
        float di = rsqrtf((float)(cnt[t] + 1u));     // +1: self loop
        di_arr[node] = di;
        float4 xv = ((const float4*)x)[node];
        ((float4*)x_scaled)[node] = make_float4(xv.x * di, xv.y * di, xv.z * di, xv.w * di);
    }
}

// P3: per bucket — edge-parallel layer-1 agg (LDS float atomics) + fused MLP.
__global__ __launch_bounds__(BSB)
void k_agg1(const unsigned* __restrict__ epack, const unsigned* __restrict__ gcur,
            const float* __restrict__ di_arr, const float* __restrict__ x_scaled,
            const float* __restrict__ W1, const float* __restrict__ b1,
            const float* __restrict__ W2,
            float* __restrict__ z_scaled, int N) {
    __shared__ float4 acc[NBW];          // 8KB accumulators
    const int b = blockIdx.x, t = threadIdx.x;
    const unsigned base = (unsigned)b * FCAP;
    const int len4 = min((int)gcur[b], FCAP) >> 2;
    acc[t] = make_float4(0.f, 0.f, 0.f, 0.f);
    __syncthreads();
    const float4* xs4 = (const float4*)x_scaled;
    const u32x4* ep4 = (const u32x4*)(epack + base);
    for (int i4 = t; i4 < len4; i4 += BSB) {
        u32x4 q = ep4[i4];
        unsigned p0 = q[0], p1 = q[1], p2 = q[2], p3 = q[3];
        // unconditional gathers (sentinel -> idx 0, L1-hot) -> 4 in flight
        float4 v0 = xs4[(p0 != NOEDGE) ? (p0 >> SH) : 0u];
        float4 v1 = xs4[(p1 != NOEDGE) ? (p1 >> SH) : 0u];
        float4 v2 = xs4[(p2 != NOEDGE) ? (p2 >> SH) : 0u];
        float4 v3 = xs4[(p3 != NOEDGE) ? (p3 >> SH) : 0u];
        if (p0 != NOEDGE) { float* a = (float*)&acc[p0 & (NBW - 1u)];
            atomicAdd(a, v0.x); atomicAdd(a + 1, v0.y); atomicAdd(a + 2, v0.z); atomicAdd(a + 3, v0.w); }
        if (p1 != NOEDGE) { float* a = (float*)&acc[p1 & (NBW - 1u)];
            atomicAdd(a, v1.x); atomicAdd(a + 1, v1.y); atomicAdd(a + 2, v1.z); atomicAdd(a + 3, v1.w); }
        if (p2 != NOEDGE) { float* a = (float*)&acc[p2 & (NBW - 1u)];
            atomicAdd(a, v2.x); atomicAdd(a + 1, v2.y); atomicAdd(a + 2, v2.z); atomicAdd(a + 3, v2.w); }
        if (p3 != NOEDGE) { float* a = (float*)&acc[p3 & (NBW - 1u)];
            atomicAdd(a, v3.x); atomicAdd(a + 1, v3.y); atomicAdd(a + 2, v3.z); atomicAdd(a + 3, v3.w); }
    }
    __syncthreads();
    const int node = b * NBW + t;
    if (node >= N) return;
    const float di = di_arr[node];
    float4 a = acc[t];
    float4 xs = xs4[node];                           // self loop
    a.x += xs.x; a.y += xs.y; a.z += xs.z; a.w += xs.w;
    const float q0 = di * a.x, q1 = di * a.y, q2 = di * a.z, q3 = di * a.w;
    float z = 0.0f;
    #pragma unroll
    for (int cc = 0; cc < 16; ++cc) {
        float h1 = q0 * W1[0 * 16 + cc] + q1 * W1[1 * 16 + cc]
                 + q2 * W1[2 * 16 + cc] + q3 * W1[3 * 16 + cc] + b1[cc];
        h1 = fmaxf(h1, 0.0f);
        z += h1 * W2[cc];
    }
    z_scaled[node] = z * di;
}

// P4: per bucket — edge-parallel layer-2 agg (scalar LDS atomics).
__global__ __launch_bounds__(BSB)
void k_agg2(const unsigned* __restrict__ epack, const unsigned* __restrict__ gcur,
            const float* __restrict__ di_arr, const float* __restrict__ z_scaled,
            const float* __restrict__ b2, float* __restrict__ out, int N) {
    __shared__ float sacc[NBW];          // 2KB accumulators
    const int b = blockIdx.x, t = threadIdx.x;
    const unsigned base = (unsigned)b * FCAP;
    const int len4 = min((int)gcur[b], FCAP) >> 2;
    sacc[t] = 0.f;
    __syncthreads();
    const u32x4* ep4 = (const u32x4*)(epack + base);
    for (int i4 = t; i4 < len4; i4 += BSB) {
        u32x4 q = ep4[i4];
        unsigned p0 = q[0], p1 = q[1], p2 = q[2], p3 = q[3];
        float v0 = z_scaled[(p0 != NOEDGE) ? (p0 >> SH) : 0u];
        float v1 = z_scaled[(p1 != NOEDGE) ? (p1 >> SH) : 0u];
        float v2 = z_scaled[(p2 != NOEDGE) ? (p2 >> SH) : 0u];
        float v3 = z_scaled[(p3 != NOEDGE) ? (p3 >> SH) : 0u];
        if (p0 != NOEDGE) atomicAdd(&sacc[p0 & (NBW - 1u)], v0);
        if (p1 != NOEDGE) atomicAdd(&sacc[p1 & (NBW - 1u)], v1);
        if (p2 != NOEDGE) atomicAdd(&sacc[p2 & (NBW - 1u)], v2);
        if (p3 != NOEDGE) atomicAdd(&sacc[p3 & (NBW - 1u)], v3);
    }
    __syncthreads();
    const int node = b * NBW + t;
    if (node >= N) return;
    const float di = di_arr[node];
    out[node] = di * (sacc[t] + z_scaled[node]) + b2[0];
}

extern "C" void kernel_launch(void* const* d_in, const int* in_sizes, int n_in,
                              void* d_out, int out_size, void* d_ws, size_t ws_size,
                              hipStream_t stream) {
    const float* x  = (const float*)d_in[0];
    const int*   ei = (const int*)d_in[1];   // [2, E] as int32
    const float* W1 = (const float*)d_in[2];
    const float* b1 = (const float*)d_in[3];
    const float* W2 = (const float*)d_in[4];
    const float* b2 = (const float*)d_in[5];

    const int N = in_sizes[0] / 4;
    const int E = in_sizes[1] / 2;
    const int* src = ei;
    const int* dst = ei + E;
    const int NA = (E + CH - 1) / CH;        // 196

    // Workspace (~22 MB): gcur | epack[NB*FCAP] | di[N] | x_scaled[N*4] |
    //   z_scaled[N]
    char* ws = (char*)d_ws;
    unsigned* gcur     = (unsigned*)ws;  ws += 4096;
    unsigned* epack    = (unsigned*)ws;  ws += (size_t)NB * FCAP * 4;
    float*    di_arr   = (float*)ws;     ws += (size_t)N * 4;
    float*    x_scaled = (float*)ws;     ws += (size_t)N * 4 * 4;
    float*    z_scaled = (float*)ws;     ws += (size_t)N * 4;
    float* out = (float*)d_out;

    hipMemsetAsync(gcur, 0, NB * sizeof(unsigned), stream);
    k_bin <<<NA, BSE, 0, stream>>>(src, dst, E, gcur, epack);
    k_deg <<<NB, BSB, 0, stream>>>(epack, gcur, x, di_arr, x_scaled, N);
    k_agg1<<<NB, BSB, 0, stream>>>(epack, gcur, di_arr, x_scaled,
                                   W1, b1, W2, z_scaled, N);
    k_agg2<<<NB, BSB, 0, stream>>>(epack, gcur, di_arr, z_scaled, b2, out, N);
}

// Round 10
// 167.020 us; speedup vs baseline: 1.3272x; 1.3272x over previous
//
#include <hip/hip_runtime.h>

// GCN 2-layer, N=200000, E=3200000.
// R21: R16 pipeline (champion, 164.2us) with k_bin re-geometried for
// occupancy. R20 post-mortem priced k_bin at ~30-35us (R17 calibration)
// vs ~7us traffic floor: CH=16384 gives only 196 blocks -> 60 CUs idle,
// ~8 waves/CU. CH=6272 -> 511 blocks, 31.5KB LDS, all co-resident,
// ~16 waves/CU on every CU. FCAP 10752->14080 (pad grows with block count;
// 10-sigma margin). build/agg1/agg2 logic identical to R16.
// 4 launches: bin -> build -> agg1 -> agg2 (+tiny gcur memset).

#define BSE   512     // bin block size
#define CH    6272    // edges per bin block -> NA=511 blocks, 25KB stage
#define NBW   512     // nodes per bucket
#define SH    9       // log2(NBW)
#define NB    391     // buckets = ceil(200000/512)
#define FCAP  14080   // slab cap: mean 8184 valid + ~3600 pad (511 blocks), +10 sigma
#define BSB   512     // build block size
#define RSTG4 ((FCAP + 4 * BSB - 1) / (4 * BSB))   // 7 x uint4 staging regs
#define NOEDGE 0xFFFFFFFFu

typedef unsigned u32x4 __attribute__((ext_vector_type(4)));

// P1: bin. count -> scan+reserve -> LDS counting sort -> linear coalesced
// write-out -> sentinel-fill pad. (R16 logic, CH=6272 geometry)
__global__ void k_bin(const int* __restrict__ src, const int* __restrict__ dst,
                      int E, unsigned* __restrict__ gcur,
                      unsigned* __restrict__ epack) {
    __shared__ unsigned stage[CH];       // 25KB: bucket-sorted chunk
    __shared__ unsigned cnt[NB];
    __shared__ unsigned ofs[NB + 1];     // exclusive scan of cnt
    __shared__ unsigned curp[NB];        // LDS scatter cursor
    __shared__ unsigned gbase[NB];       // global slab base per bucket
    __shared__ unsigned wsum[BSE / 64];
    const int b = blockIdx.x, t = threadIdx.x;
    for (int i = t; i < NB; i += BSE) cnt[i] = 0;
    __syncthreads();
    const int lo = b * CH, hi = min(E, lo + CH);
    const int n = hi - lo;
    const int aligned = n & ~3;
    // pass 1: count per bucket
    for (int i = 4 * t; i + 3 < n; i += 4 * BSE) {
        int4 d4 = *(const int4*)(dst + lo + i);
        atomicAdd(&cnt[((unsigned)d4.x) >> SH], 1u);
        atomicAdd(&cnt[((unsigned)d4.y) >> SH], 1u);
        atomicAdd(&cnt[((unsigned)d4.z) >> SH], 1u);
        atomicAdd(&cnt[((unsigned)d4.w) >> SH], 1u);
    }
    for (int i = aligned + t; i < n; i += BSE)
        atomicAdd(&cnt[((unsigned)dst[lo + i]) >> SH], 1u);
    __syncthreads();
    // block scan of bucket counts (shuffle scan, 512 lanes covers NB=391)
    const unsigned c = (t < NB) ? cnt[t] : 0u;
    unsigned v = c;
    #pragma unroll
    for (int off = 1; off < 64; off <<= 1) {
        unsigned u = __shfl_up(v, off);
        if ((t & 63) >= off) v += u;
    }
    if ((t & 63) == 63) wsum[t >> 6] = v;
    __syncthreads();
    if (t < BSE / 64) {
        unsigned w = wsum[t];
        #pragma unroll
        for (int off = 1; off < BSE / 64; off <<= 1) {
            unsigned u = __shfl_up(w, off);
            if (t >= off) w += u;
        }
        wsum[t] = w;
    }
    __syncthreads();
    const unsigned incl = v + ((t >> 6) ? wsum[(t >> 6) - 1] : 0u);
    const unsigned excl = incl - c;
    if (t < NB) {
        ofs[t] = excl;
        curp[t] = excl;
        unsigned pad = (c + 15u) & ~15u;             // 64B-aligned reservation
        unsigned o = pad ? atomicAdd(&gcur[t], pad) : 0u;
        gbase[t] = (unsigned)t * FCAP + o;
    }
    if (t == NB - 1) ofs[NB] = incl;                 // = n
    __syncthreads();
    // pass 2: counting-sort edges into LDS
    for (int i = 4 * t; i + 3 < n; i += 4 * BSE) {
        int4 d4 = *(const int4*)(dst + lo + i);
        int4 s4 = *(const int4*)(src + lo + i);
        unsigned k0 = ((unsigned)d4.x) >> SH, k1 = ((unsigned)d4.y) >> SH;
        unsigned k2 = ((unsigned)d4.z) >> SH, k3 = ((unsigned)d4.w) >> SH;
        unsigned p0 = atomicAdd(&curp[k0], 1u);
        unsigned p1 = atomicAdd(&curp[k1], 1u);
        unsigned p2 = atomicAdd(&curp[k2], 1u);
        unsigned p3 = atomicAdd(&curp[k3], 1u);
        stage[p0] = ((unsigned)s4.x << SH) | (((unsigned)d4.x) & (NBW - 1u));
        stage[p1] = ((unsigned)s4.y << SH) | (((unsigned)d4.y) & (NBW - 1u));
        stage[p2] = ((unsigned)s4.z << SH) | (((unsigned)d4.z) & (NBW - 1u));
        stage[p3] = ((unsigned)s4.w << SH) | (((unsigned)d4.w) & (NBW - 1u));
    }
    for (int i = aligned + t; i < n; i += BSE) {
        unsigned d = (unsigned)dst[lo + i];
        unsigned k = d >> SH;
        unsigned pos = atomicAdd(&curp[k], 1u);
        stage[pos] = ((unsigned)src[lo + i] << SH) | (d & (NBW - 1u));
    }
    __syncthreads();
    // pass 3: linear write-out (bucket by binary search over scanned offsets)
    for (int p0 = 4 * t; p0 < n; p0 += 4 * BSE) {
        unsigned k = 0;                              // largest k: ofs[k] <= p0
        #pragma unroll
        for (unsigned s = 256; s; s >>= 1) {
            unsigned cand = k + s;
            if (cand <= NB && ofs[cand] <= (unsigned)p0) k = cand;
        }
        #pragma unroll
        for (int j = 0; j < 4; ++j) {
            int p = p0 + j;
            if (p >= n) break;
            while (ofs[k + 1] <= (unsigned)p) ++k;   // rare boundary advance
            unsigned addr = gbase[k] + ((unsigned)p - ofs[k]);
            if (addr < (k + 1u) * FCAP) epack[addr] = stage[p];
        }
    }
    // sentinel-fill the pad of each cell (disjoint regions, no sync needed)
    for (int i = t; i < NB; i += BSE) {
        unsigned s = gbase[i] + cnt[i];
        unsigned e = gbase[i] + ((cnt[i] + 15u) & ~15u);
        unsigned kend = ((unsigned)i + 1u) * FCAP;
        if (e > kend) e = kend;
        for (unsigned p = s; p < e; ++p) epack[p] = NOEDGE;
    }
}

// P2: per bucket — stage slab into registers (7x 16B loads, static indexed:
// VGPRs, no scratch), count per node, wave-shuffle scan, counting sort into
// LDS, coalesced writeback. Emits meta = excl|(c<<14), x_scaled. (R16 logic)
__global__ void k_build(unsigned* __restrict__ epack, const unsigned* __restrict__ gcur,
                        const float* __restrict__ x,
                        unsigned* __restrict__ meta,
                        float* __restrict__ x_scaled, int N) {
    __shared__ unsigned stage[FCAP];     // sorted src lists only (55KB)
    __shared__ unsigned cnt[BSB];
    __shared__ unsigned cur[BSB];
    __shared__ unsigned wsum[BSB / 64];
    __shared__ unsigned s_lenv;
    const int k = blockIdx.x, t = threadIdx.x;     // 512 threads
    const unsigned base = (unsigned)k * FCAP;
    const int len = min((int)gcur[k], FCAP);       // multiple of 16
    const int len4 = len >> 2;
    const u32x4* ep4 = (const u32x4*)(epack + base);
    u32x4 r4[RSTG4];                               // 28 VGPRs, static indexed
    #pragma unroll
    for (int j = 0; j < RSTG4; ++j) {
        int i4 = t + j * BSB;                      // coalesced 16B loads
        if (i4 < len4) r4[j] = ep4[i4];
        else           r4[j] = (u32x4){NOEDGE, NOEDGE, NOEDGE, NOEDGE};
    }
    cnt[t] = 0;
    __syncthreads();
    #pragma unroll
    for (int j = 0; j < RSTG4; ++j) {
        #pragma unroll
        for (int e = 0; e < 4; ++e) {
            unsigned p = r4[j][e];
            if (p != NOEDGE) atomicAdd(&cnt[p & (NBW - 1u)], 1u);
        }
    }
    __syncthreads();
    const unsigned c = cnt[t];
    unsigned v = c;                                // inclusive wave-scan (64)
    #pragma unroll
    for (int off = 1; off < 64; off <<= 1) {
        unsigned u = __shfl_up(v, off);
        if ((t & 63) >= off) v += u;
    }
    if ((t & 63) == 63) wsum[t >> 6] = v;
    __syncthreads();
    if (t < BSB / 64) {                            // scan the 8 wave sums
        unsigned w = wsum[t];
        #pragma unroll
        for (int off = 1; off < BSB / 64; off <<= 1) {
            unsigned u = __shfl_up(w, off);
            if (t >= off) w += u;
        }
        wsum[t] = w;                               // inclusive
    }
    __syncthreads();
    const unsigned incl = v + ((t >> 6) ? wsum[(t >> 6) - 1] : 0u);
    const unsigned excl = incl - c;
    cur[t] = excl;
    if (t == BSB - 1) s_lenv = incl;               // valid edge count
    const int node = k * NBW + t;
    if (node < N) {
        meta[node] = excl | (c << 14);             // excl<14080<2^14? no: <2^14=16384 OK
        float di = rsqrtf((float)(c + 1u));        // +1: self loop
        float4 xv = ((const float4*)x)[node];
        ((float4*)x_scaled)[node] = make_float4(xv.x * di, xv.y * di, xv.z * di, xv.w * di);
    }
    __syncthreads();
    #pragma unroll
    for (int j = 0; j < RSTG4; ++j) {
        #pragma unroll
        for (int e = 0; e < 4; ++e) {
            unsigned p = r4[j][e];
            if (p != NOEDGE) {
                unsigned pos = atomicAdd(&cur[p & (NBW - 1u)], 1u);
                if (pos < FCAP) stage[pos] = p >> SH;  // sorted src lists
            }
        }
    }
    __syncthreads();
    const int lenv = min((int)s_lenv, FCAP);
    for (int i = 4 * t; i + 3 < lenv; i += 4 * BSB)  // coalesced writeback
        *(int4*)(epack + base + i) = *(const int4*)&stage[i];
    if (t < (lenv & 3)) epack[base + (lenv & ~3) + t] = stage[(lenv & ~3) + t];
}

// P3: pull-mode layer-1 aggregation + fused node math (no atomics). (R16)
__global__ void k_agg1(const unsigned* __restrict__ esorted, const unsigned* __restrict__ meta,
                       const float* __restrict__ x_scaled,
                       const float* __restrict__ W1, const float* __restrict__ b1,
                       const float* __restrict__ W2,
                       float* __restrict__ z_scaled, int N) {
    int node = blockIdx.x * blockDim.x + threadIdx.x;
    if (node >= N) return;
    unsigned m = meta[node];
    unsigned c = m >> 14;
    unsigned lo = (unsigned)(node >> SH) * FCAP + (m & 16383u);
    unsigned hi = lo + c;
    float di = rsqrtf((float)(c + 1u));
    const float4* xs4 = (const float4*)x_scaled;
    float4 a0 = xs4[node];                          // self loop
    float4 a1 = make_float4(0.f, 0.f, 0.f, 0.f);
    float4 a2 = make_float4(0.f, 0.f, 0.f, 0.f);
    float4 a3 = make_float4(0.f, 0.f, 0.f, 0.f);
    unsigned i = lo;
    for (; i + 3 < hi; i += 4) {                    // 4 gathers in flight
        float4 v0 = xs4[esorted[i]],     v1 = xs4[esorted[i + 1]];
        float4 v2 = xs4[esorted[i + 2]], v3 = xs4[esorted[i + 3]];
        a0.x += v0.x; a0.y += v0.y; a0.z += v0.z; a0.w += v0.w;
        a1.x += v1.x; a1.y += v1.y; a1.z += v1.z; a1.w += v1.w;
        a2.x += v2.x; a2.y += v2.y; a2.z += v2.z; a2.w += v2.w;
        a3.x += v3.x; a3.y += v3.y; a3.z += v3.z; a3.w += v3.w;
    }
    for (; i < hi; ++i) {
        float4 v = xs4[esorted[i]];
        a0.x += v.x; a0.y += v.y; a0.z += v.z; a0.w += v.w;
    }
    float p0 = di * (a0.x + a1.x + a2.x + a3.x);
    float p1 = di * (a0.y + a1.y + a2.y + a3.y);
    float p2 = di * (a0.z + a1.z + a2.z + a3.z);
    float p3 = di * (a0.w + a1.w + a2.w + a3.w);
    float z = 0.0f;
    #pragma unroll
    for (int cc = 0; cc < 16; ++cc) {
        float h1 = p0 * W1[0 * 16 + cc] + p1 * W1[1 * 16 + cc]
                 + p2 * W1[2 * 16 + cc] + p3 * W1[3 * 16 + cc] + b1[cc];
        h1 = fmaxf(h1, 0.0f);
        z += h1 * W2[cc];
    }
    z_scaled[node] = z * di;
}

// P4: pull-mode layer-2 aggregation (no atomics). (R16)
__global__ void k_agg2(const unsigned* __restrict__ esorted, const unsigned* __restrict__ meta,
                       const float* __restrict__ z_scaled,
                       const float* __restrict__ b2, float* __restrict__ out, int N) {
    int node = blockIdx.x * blockDim.x + threadIdx.x;
    if (node >= N) return;
    unsigned m = meta[node];
    unsigned c = m >> 14;
    unsigned lo = (unsigned)(node >> SH) * FCAP + (m & 16383u);
    unsigned hi = lo + c;
    float di = rsqrtf((float)(c + 1u));
    float a0 = z_scaled[node], a1 = 0.f, a2 = 0.f, a3 = 0.f;  // self loop in a0
    unsigned i = lo;
    for (; i + 3 < hi; i += 4) {
        a0 += z_scaled[esorted[i]];
        a1 += z_scaled[esorted[i + 1]];
        a2 += z_scaled[esorted[i + 2]];
        a3 += z_scaled[esorted[i + 3]];
    }
    for (; i < hi; ++i) a0 += z_scaled[esorted[i]];
    out[node] = di * (a0 + a1 + a2 + a3) + b2[0];
}

extern "C" void kernel_launch(void* const* d_in, const int* in_sizes, int n_in,
                              void* d_out, int out_size, void* d_ws, size_t ws_size,
                              hipStream_t stream) {
    const float* x  = (const float*)d_in[0];
    const int*   ei = (const int*)d_in[1];   // [2, E] as int32
    const float* W1 = (const float*)d_in[2];
    const float* b1 = (const float*)d_in[3];
    const float* W2 = (const float*)d_in[4];
    const float* b2 = (const float*)d_in[5];

    const int N = in_sizes[0] / 4;
    const int E = in_sizes[1] / 2;
    const int* src = ei;
    const int* dst = ei + E;
    const int NA = (E + CH - 1) / CH;        // 511

    // Workspace (~27 MB): gcur | epack[NB*FCAP] | meta[N] | x_scaled[N*4] |
    //   z_scaled[N]   (poison fills show ws buffer is 256MiB — plenty)
    char* ws = (char*)d_ws;
    unsigned* gcur     = (unsigned*)ws;  ws += 4096;
    unsigned* epack    = (unsigned*)ws;  ws += (size_t)NB * FCAP * 4;
    unsigned* meta     = (unsigned*)ws;  ws += (size_t)N * 4;
    float*    x_scaled = (float*)ws;     ws += (size_t)N * 4 * 4;
    float*    z_scaled = (float*)ws;     ws += (size_t)N * 4;
    float* out = (float*)d_out;

    hipMemsetAsync(gcur, 0, NB * sizeof(unsigned), stream);
    k_bin  <<<NA, BSE, 0, stream>>>(src, dst, E, gcur, epack);
    k_build<<<NB, BSB, 0, stream>>>(epack, gcur, x, meta, x_scaled, N);
    k_agg1 <<<(N + 255) / 256, 256, 0, stream>>>(epack, meta, x_scaled,
                                                 W1, b1, W2, z_scaled, N);
    k_agg2 <<<(N + 255) / 256, 256, 0, stream>>>(epack, meta, z_scaled, b2, out, N);
}

// Round 11
// 165.448 us; speedup vs baseline: 1.3398x; 1.0095x over previous
//
#include <hip/hip_runtime.h>

// GCN 2-layer, N=200000, E=3200000.
// R22: INSTRUMENTED round. Pipeline = R16 champion (164.2us), byte-identical
// data path. k_bin launched at 2x grid: blocks b<NA do real work; b>=NA run
// the identical code on the same chunks into a scratch slab (epack2/gcur2).
// The doubled dispatch (~2x k_bin) exceeds the 43us harness fills -> appears
// in rocprof top-5 WITH counters (VALUBusy/Occ/FETCH/LDS-conflict), and
// k_bin's true cost = dur - 164.2. Five blind micro-opts were null; this
// buys the evidence to pick the next real lever.

#define BSE   512     // bin block size
#define CH    16384   // edges per bin block (LDS stage = 64KB)
#define NBW   512     // nodes per bucket
#define SH    9       // log2(NBW)
#define NB    391     // buckets = ceil(200000/512)
#define FCAP  10752   // slab capacity (valid mean 8184 + pad mean ~1470, +10 sigma)
#define BSB   512     // build block size
#define RSTG  ((FCAP + BSB - 1) / BSB)   // 21 staging regs
#define NOEDGE 0xFFFFFFFFu

// P1: bin (R16 logic). count -> scan+reserve -> LDS counting sort -> linear
// coalesced write-out -> sentinel-fill pad. Doubled grid: b>=NA replays
// chunk (b-NA) into the scratch slab for rocprof visibility.
__global__ void k_bin(const int* __restrict__ src, const int* __restrict__ dst,
                      int E, unsigned* __restrict__ gcur_r, unsigned* __restrict__ gcur_s,
                      unsigned* __restrict__ epack_r, unsigned* __restrict__ epack_s,
                      int NA) {
    __shared__ unsigned stage[CH];       // 64KB: bucket-sorted chunk
    __shared__ unsigned cnt[NB];
    __shared__ unsigned ofs[NB + 1];     // exclusive scan of cnt
    __shared__ unsigned curp[NB];        // LDS scatter cursor
    __shared__ unsigned gbase[NB];       // global slab base per bucket
    __shared__ unsigned wsum[BSE / 64];
    const int breal = (int)blockIdx.x < NA;
    const int b = breal ? (int)blockIdx.x : (int)blockIdx.x - NA;
    unsigned* __restrict__ gcur  = breal ? gcur_r  : gcur_s;
    unsigned* __restrict__ epack = breal ? epack_r : epack_s;
    const int t = threadIdx.x;
    for (int i = t; i < NB; i += BSE) cnt[i] = 0;
    __syncthreads();
    const int lo = b * CH, hi = min(E, lo + CH);
    const int n = hi - lo;
    const int aligned = n & ~3;
    // pass 1: count per bucket
    for (int i = 4 * t; i + 3 < n; i += 4 * BSE) {
        int4 d4 = *(const int4*)(dst + lo + i);
        atomicAdd(&cnt[((unsigned)d4.x) >> SH], 1u);
        atomicAdd(&cnt[((unsigned)d4.y) >> SH], 1u);
        atomicAdd(&cnt[((unsigned)d4.z) >> SH], 1u);
        atomicAdd(&cnt[((unsigned)d4.w) >> SH], 1u);
    }
    for (int i = aligned + t; i < n; i += BSE)
        atomicAdd(&cnt[((unsigned)dst[lo + i]) >> SH], 1u);
    __syncthreads();
    // block scan of bucket counts (shuffle scan, 512 lanes covers NB=391)
    const unsigned c = (t < NB) ? cnt[t] : 0u;
    unsigned v = c;
    #pragma unroll
    for (int off = 1; off < 64; off <<= 1) {
        unsigned u = __shfl_up(v, off);
        if ((t & 63) >= off) v += u;
    }
    if ((t & 63) == 63) wsum[t >> 6] = v;
    __syncthreads();
    if (t < BSE / 64) {
        unsigned w = wsum[t];
        #pragma unroll
        for (int off = 1; off < BSE / 64; off <<= 1) {
            unsigned u = __shfl_up(w, off);
            if (t >= off) w += u;
        }
        wsum[t] = w;
    }
    __syncthreads();
    const unsigned incl = v + ((t >> 6) ? wsum[(t >> 6) - 1] : 0u);
    const unsigned excl = incl - c;
    if (t < NB) {
        ofs[t] = excl;
        curp[t] = excl;
        unsigned pad = (c + 15u) & ~15u;             // 64B-aligned reservation
        unsigned o = pad ? atomicAdd(&gcur[t], pad) : 0u;
        gbase[t] = (unsigned)t * FCAP + o;
    }
    if (t == NB - 1) ofs[NB] = incl;                 // = n
    __syncthreads();
    // pass 2: counting-sort edges into LDS
    for (int i = 4 * t; i + 3 < n; i += 4 * BSE) {
        int4 d4 = *(const int4*)(dst + lo + i);
        int4 s4 = *(const int4*)(src + lo + i);
        unsigned k0 = ((unsigned)d4.x) >> SH, k1 = ((unsigned)d4.y) >> SH;
        unsigned k2 = ((unsigned)d4.z) >> SH, k3 = ((unsigned)d4.w) >> SH;
        unsigned p0 = atomicAdd(&curp[k0], 1u);
        unsigned p1 = atomicAdd(&curp[k1], 1u);
        unsigned p2 = atomicAdd(&curp[k2], 1u);
        unsigned p3 = atomicAdd(&curp[k3], 1u);
        stage[p0] = ((unsigned)s4.x << SH) | (((unsigned)d4.x) & (NBW - 1u));
        stage[p1] = ((unsigned)s4.y << SH) | (((unsigned)d4.y) & (NBW - 1u));
        stage[p2] = ((unsigned)s4.z << SH) | (((unsigned)d4.z) & (NBW - 1u));
        stage[p3] = ((unsigned)s4.w << SH) | (((unsigned)d4.w) & (NBW - 1u));
    }
    for (int i = aligned + t; i < n; i += BSE) {
        unsigned d = (unsigned)dst[lo + i];
        unsigned k = d >> SH;
        unsigned pos = atomicAdd(&curp[k], 1u);
        stage[pos] = ((unsigned)src[lo + i] << SH) | (d & (NBW - 1u));
    }
    __syncthreads();
    // pass 3: linear write-out (bucket by binary search over scanned offsets)
    for (int p0 = 4 * t; p0 < n; p0 += 4 * BSE) {
        unsigned k = 0;                              // largest k: ofs[k] <= p0
        #pragma unroll
        for (unsigned s = 256; s; s >>= 1) {
            unsigned cand = k + s;
            if (cand <= NB && ofs[cand] <= (unsigned)p0) k = cand;
        }
        #pragma unroll
        for (int j = 0; j < 4; ++j) {
            int p = p0 + j;
            if (p >= n) break;
            while (ofs[k + 1] <= (unsigned)p) ++k;   // rare boundary advance
            unsigned addr = gbase[k] + ((unsigned)p - ofs[k]);
            if (addr < (k + 1u) * FCAP) epack[addr] = stage[p];
        }
    }
    // sentinel-fill the pad of each cell (disjoint regions, no sync needed)
    for (int i = t; i < NB; i += BSE) {
        unsigned s = gbase[i] + cnt[i];
        unsigned e = gbase[i] + ((cnt[i] + 15u) & ~15u);
        unsigned kend = ((unsigned)i + 1u) * FCAP;
        if (e > kend) e = kend;
        for (unsigned p = s; p < e; ++p) epack[p] = NOEDGE;
    }
}

// P2: per bucket — stage slab straight into registers (static unroll: VGPRs,
// no scratch), count per node, wave-shuffle scan, counting sort into LDS,
// coalesced writeback. Emits meta = excl|(c<<14), x_scaled. (R16 exact)
__global__ void k_build(unsigned* __restrict__ epack, const unsigned* __restrict__ gcur,
                        const float* __restrict__ x,
                        unsigned* __restrict__ meta,
                        float* __restrict__ x_scaled, int N) {
    __shared__ unsigned stage[FCAP];     // sorted src lists only
    __shared__ unsigned cnt[BSB];
    __shared__ unsigned cur[BSB];
    __shared__ unsigned wsum[BSB / 64];
    __shared__ unsigned s_lenv;
    const int k = blockIdx.x, t = threadIdx.x;     // 512 threads
    const unsigned base = (unsigned)k * FCAP;
    const int len = min((int)gcur[k], FCAP);       // includes sentinel pad
    unsigned r[RSTG];                              // static unroll -> VGPRs
    #pragma unroll
    for (int j = 0; j < RSTG; ++j) {
        int i = t + j * BSB;                       // coalesced 4B loads
        r[j] = (i < len) ? epack[base + i] : NOEDGE;
    }
    cnt[t] = 0;
    __syncthreads();
    #pragma unroll
    for (int j = 0; j < RSTG; ++j) {
        unsigned p = r[j];
        if (p != NOEDGE) atomicAdd(&cnt[p & (NBW - 1u)], 1u);
    }
    __syncthreads();
    const unsigned c = cnt[t];
    unsigned v = c;                                // inclusive wave-scan (64)
    #pragma unroll
    for (int off = 1; off < 64; off <<= 1) {
        unsigned u = __shfl_up(v, off);
        if ((t & 63) >= off) v += u;
    }
    if ((t & 63) == 63) wsum[t >> 6] = v;
    __syncthreads();
    if (t < BSB / 64) {                            // scan the 8 wave sums
        unsigned w = wsum[t];
        #pragma unroll
        for (int off = 1; off < BSB / 64; off <<= 1) {
            unsigned u = __shfl_up(w, off);
            if (t >= off) w += u;
        }
        wsum[t] = w;                               // inclusive
    }
    __syncthreads();
    const unsigned incl = v + ((t >> 6) ? wsum[(t >> 6) - 1] : 0u);
    const unsigned excl = incl - c;
    cur[t] = excl;
    if (t == BSB - 1) s_lenv = incl;               // valid edge count
    const int node = k * NBW + t;
    if (node < N) {
        meta[node] = excl | (c << 14);             // both < 2^14
        float di = rsqrtf((float)(c + 1u));        // +1: self loop
        float4 xv = ((const float4*)x)[node];
        ((float4*)x_scaled)[node] = make_float4(xv.x * di, xv.y * di, xv.z * di, xv.w * di);
    }
    __syncthreads();
    #pragma unroll
    for (int j = 0; j < RSTG; ++j) {
        unsigned p = r[j];
        if (p != NOEDGE) {
            unsigned pos = atomicAdd(&cur[p & (NBW - 1u)], 1u);
            stage[pos] = p >> SH;                  // sorted src lists
        }
    }
    __syncthreads();
    const int lenv = (int)s_lenv;
    for (int i = 4 * t; i + 3 < lenv; i += 4 * BSB)  // coalesced writeback
        *(int4*)(epack + base + i) = *(const int4*)&stage[i];
    if (t < (lenv & 3)) epack[base + (lenv & ~3) + t] = stage[(lenv & ~3) + t];
}

// P3: pull-mode layer-1 aggregation + fused node math (no atomics). (R16)
__global__ void k_agg1(const unsigned* __restrict__ esorted, const unsigned* __restrict__ meta,
                       const float* __restrict__ x_scaled,
                       const float* __restrict__ W1, const float* __restrict__ b1,
                       const float* __restrict__ W2,
                       float* __restrict__ z_scaled, int N) {
    int node = blockIdx.x * blockDim.x + threadIdx.x;
    if (node >= N) return;
    unsigned m = meta[node];
    unsigned c = m >> 14;
    unsigned lo = (unsigned)(node >> SH) * FCAP + (m & 16383u);
    unsigned hi = lo + c;
    float di = rsqrtf((float)(c + 1u));
    const float4* xs4 = (const float4*)x_scaled;
    float4 a0 = xs4[node];                          // self loop
    float4 a1 = make_float4(0.f, 0.f, 0.f, 0.f);
    float4 a2 = make_float4(0.f, 0.f, 0.f, 0.f);
    float4 a3 = make_float4(0.f, 0.f, 0.f, 0.f);
    unsigned i = lo;
    for (; i + 3 < hi; i += 4) {                    // 4 gathers in flight
        float4 v0 = xs4[esorted[i]],     v1 = xs4[esorted[i + 1]];
        float4 v2 = xs4[esorted[i + 2]], v3 = xs4[esorted[i + 3]];
        a0.x += v0.x; a0.y += v0.y; a0.z += v0.z; a0.w += v0.w;
        a1.x += v1.x; a1.y += v1.y; a1.z += v1.z; a1.w += v1.w;
        a2.x += v2.x; a2.y += v2.y; a2.z += v2.z; a2.w += v2.w;
        a3.x += v3.x; a3.y += v3.y; a3.z += v3.z; a3.w += v3.w;
    }
    for (; i < hi; ++i) {
        float4 v = xs4[esorted[i]];
        a0.x += v.x; a0.y += v.y; a0.z += v.z; a0.w += v.w;
    }
    float p0 = di * (a0.x + a1.x + a2.x + a3.x);
    float p1 = di * (a0.y + a1.y + a2.y + a3.y);
    float p2 = di * (a0.z + a1.z + a2.z + a3.z);
    float p3 = di * (a0.w + a1.w + a2.w + a3.w);
    float z = 0.0f;
    #pragma unroll
    for (int cc = 0; cc < 16; ++cc) {
        float h1 = p0 * W1[0 * 16 + cc] + p1 * W1[1 * 16 + cc]
                 + p2 * W1[2 * 16 + cc] + p3 * W1[3 * 16 + cc] + b1[cc];
        h1 = fmaxf(h1, 0.0f);
        z += h1 * W2[cc];
    }
    z_scaled[node] = z * di;
}

// P4: pull-mode layer-2 aggregation (no atomics). (R16)
__global__ void k_agg2(const unsigned* __restrict__ esorted, const unsigned* __restrict__ meta,
                       const float* __restrict__ z_scaled,
                       const float* __restrict__ b2, float* __restrict__ out, int N) {
    int node = blockIdx.x * blockDim.x + threadIdx.x;
    if (node >= N) return;
    unsigned m = meta[node];
    unsigned c = m >> 14;
    unsigned lo = (unsigned)(node >> SH) * FCAP + (m & 16383u);
    unsigned hi = lo + c;
    float di = rsqrtf((float)(c + 1u));
    float a0 = z_scaled[node], a1 = 0.f, a2 = 0.f, a3 = 0.f;  // self loop in a0
    unsigned i = lo;
    for (; i + 3 < hi; i += 4) {
        a0 += z_scaled[esorted[i]];
        a1 += z_scaled[esorted[i + 1]];
        a2 += z_scaled[esorted[i + 2]];
        a3 += z_scaled[esorted[i + 3]];
    }
    for (; i < hi; ++i) a0 += z_scaled[esorted[i]];
    out[node] = di * (a0 + a1 + a2 + a3) + b2[0];
}

extern "C" void kernel_launch(void* const* d_in, const int* in_sizes, int n_in,
                              void* d_out, int out_size, void* d_ws, size_t ws_size,
                              hipStream_t stream) {
    const float* x  = (const float*)d_in[0];
    const int*   ei = (const int*)d_in[1];   // [2, E] as int32
    const float* W1 = (const float*)d_in[2];
    const float* b1 = (const float*)d_in[3];
    const float* W2 = (const float*)d_in[4];
    const float* b2 = (const float*)d_in[5];

    const int N = in_sizes[0] / 4;
    const int E = in_sizes[1] / 2;
    const int* src = ei;
    const int* dst = ei + E;
    const int NA = (E + CH - 1) / CH;        // 196

    // Workspace (~36 MB): gcur | gcur2 | epack | epack2(scratch) | meta |
    //   x_scaled | z_scaled
    char* ws = (char*)d_ws;
    unsigned* gcur     = (unsigned*)ws;  ws += 4096;
    unsigned* gcur2    = (unsigned*)ws;  ws += 4096;
    unsigned* epack    = (unsigned*)ws;  ws += (size_t)NB * FCAP * 4;
    unsigned* epack2   = (unsigned*)ws;  ws += (size_t)NB * FCAP * 4;
    unsigned* meta     = (unsigned*)ws;  ws += (size_t)N * 4;
    float*    x_scaled = (float*)ws;     ws += (size_t)N * 4 * 4;
    float*    z_scaled = (float*)ws;     ws += (size_t)N * 4;
    float* out = (float*)d_out;

    hipMemsetAsync(gcur, 0, 8192, stream);   // zeroes gcur AND gcur2
    k_bin  <<<2 * NA, BSE, 0, stream>>>(src, dst, E, gcur, gcur2,
                                        epack, epack2, NA);
    k_build<<<NB, BSB, 0, stream>>>(epack, gcur, x, meta, x_scaled, N);
    k_agg1 <<<(N + 255) / 256, 256, 0, stream>>>(epack, meta, x_scaled,
                                                 W1, b1, W2, z_scaled, N);
    k_agg2 <<<(N + 255) / 256, 256, 0, stream>>>(epack, meta, z_scaled, b2, out, N);
}

// Round 12
// 162.053 us; speedup vs baseline: 1.3679x; 1.0210x over previous
//
#include <hip/hip_runtime.h>

// GCN 2-layer, N=200000, E=3200000.
// R23 = R16 champion restored (164.2us), instrumentation removed.
// Ceiling evidence (R14-R22): dur_us = ~84-88us harness poison-fills
// (HBM-roofline-bound) + ~76-80us kernels. Kernel floors: 6.4M random
// L2-line gathers in agg1/agg2 (~25-40us, every reordering refuted:
// ILP/NT/deg-sort/edge-parallel/fusion), bin+build stream+LDS-sort
// (~30-38us; occupancy/vector/scratch nulls). Nine mechanisms tested;
// only scatter-linearization (R16, -6us) was real. At structural floor.
// 4 launches: bin -> build -> agg1 -> agg2 (+tiny gcur memset).

#define BSE   512     // bin block size
#define CH    16384   // edges per bin block (LDS stage = 64KB)
#define NBW   512     // nodes per bucket
#define SH    9       // log2(NBW)
#define NB    391     // buckets = ceil(200000/512)
#define FCAP  10752   // slab capacity (valid mean 8184 + pad mean ~1470, +10 sigma)
#define BSB   512     // build block size
#define RSTG  ((FCAP + BSB - 1) / BSB)   // 21 staging regs
#define NOEDGE 0xFFFFFFFFu

// P1: bin. count -> scan+reserve -> LDS counting sort -> linear coalesced
// write-out -> sentinel-fill pad.
__global__ void k_bin(const int* __restrict__ src, const int* __restrict__ dst,
                      int E, unsigned* __restrict__ gcur,
                      unsigned* __restrict__ epack) {
    __shared__ unsigned stage[CH];       // 64KB: bucket-sorted chunk
    __shared__ unsigned cnt[NB];
    __shared__ unsigned ofs[NB + 1];     // exclusive scan of cnt
    __shared__ unsigned curp[NB];        // LDS scatter cursor
    __shared__ unsigned gbase[NB];       // global slab base per bucket
    __shared__ unsigned wsum[BSE / 64];
    const int b = blockIdx.x, t = threadIdx.x;
    for (int i = t; i < NB; i += BSE) cnt[i] = 0;
    __syncthreads();
    const int lo = b * CH, hi = min(E, lo + CH);
    const int n = hi - lo;
    const int aligned = n & ~3;
    // pass 1: count per bucket
    for (int i = 4 * t; i + 3 < n; i += 4 * BSE) {
        int4 d4 = *(const int4*)(dst + lo + i);
        atomicAdd(&cnt[((unsigned)d4.x) >> SH], 1u);
        atomicAdd(&cnt[((unsigned)d4.y) >> SH], 1u);
        atomicAdd(&cnt[((unsigned)d4.z) >> SH], 1u);
        atomicAdd(&cnt[((unsigned)d4.w) >> SH], 1u);
    }
    for (int i = aligned + t; i < n; i += BSE)
        atomicAdd(&cnt[((unsigned)dst[lo + i]) >> SH], 1u);
    __syncthreads();
    // block scan of bucket counts (shuffle scan, 512 lanes covers NB=391)
    const unsigned c = (t < NB) ? cnt[t] : 0u;
    unsigned v = c;
    #pragma unroll
    for (int off = 1; off < 64; off <<= 1) {
        unsigned u = __shfl_up(v, off);
        if ((t & 63) >= off) v += u;
    }
    if ((t & 63) == 63) wsum[t >> 6] = v;
    __syncthreads();
    if (t < BSE / 64) {
        unsigned w = wsum[t];
        #pragma unroll
        for (int off = 1; off < BSE / 64; off <<= 1) {
            unsigned u = __shfl_up(w, off);
            if (t >= off) w += u;
        }
        wsum[t] = w;
    }
    __syncthreads();
    const unsigned incl = v + ((t >> 6) ? wsum[(t >> 6) - 1] : 0u);
    const unsigned excl = incl - c;
    if (t < NB) {
        ofs[t] = excl;
        curp[t] = excl;
        unsigned pad = (c + 15u) & ~15u;             // 64B-aligned reservation
        unsigned o = pad ? atomicAdd(&gcur[t], pad) : 0u;
        gbase[t] = (unsigned)t * FCAP + o;
    }
    if (t == NB - 1) ofs[NB] = incl;                 // = n
    __syncthreads();
    // pass 2: counting-sort edges into LDS
    for (int i = 4 * t; i + 3 < n; i += 4 * BSE) {
        int4 d4 = *(const int4*)(dst + lo + i);
        int4 s4 = *(const int4*)(src + lo + i);
        unsigned k0 = ((unsigned)d4.x) >> SH, k1 = ((unsigned)d4.y) >> SH;
        unsigned k2 = ((unsigned)d4.z) >> SH, k3 = ((unsigned)d4.w) >> SH;
        unsigned p0 = atomicAdd(&curp[k0], 1u);
        unsigned p1 = atomicAdd(&curp[k1], 1u);
        unsigned p2 = atomicAdd(&curp[k2], 1u);
        unsigned p3 = atomicAdd(&curp[k3], 1u);
        stage[p0] = ((unsigned)s4.x << SH) | (((unsigned)d4.x) & (NBW - 1u));
        stage[p1] = ((unsigned)s4.y << SH) | (((unsigned)d4.y) & (NBW - 1u));
        stage[p2] = ((unsigned)s4.z << SH) | (((unsigned)d4.z) & (NBW - 1u));
        stage[p3] = ((unsigned)s4.w << SH) | (((unsigned)d4.w) & (NBW - 1u));
    }
    for (int i = aligned + t; i < n; i += BSE) {
        unsigned d = (unsigned)dst[lo + i];
        unsigned k = d >> SH;
        unsigned pos = atomicAdd(&curp[k], 1u);
        stage[pos] = ((unsigned)src[lo + i] << SH) | (d & (NBW - 1u));
    }
    __syncthreads();
    // pass 3: linear write-out. 4 consecutive positions per thread; one
    // binary search, boundary-advance for the rest. Lanes write contiguous
    // addresses within each bucket run.
    for (int p0 = 4 * t; p0 < n; p0 += 4 * BSE) {
        unsigned k = 0;                              // largest k: ofs[k] <= p0
        #pragma unroll
        for (unsigned s = 256; s; s >>= 1) {
            unsigned cand = k + s;
            if (cand <= NB && ofs[cand] <= (unsigned)p0) k = cand;
        }
        #pragma unroll
        for (int j = 0; j < 4; ++j) {
            int p = p0 + j;
            if (p >= n) break;
            while (ofs[k + 1] <= (unsigned)p) ++k;   // rare boundary advance
            unsigned addr = gbase[k] + ((unsigned)p - ofs[k]);
            if (addr < (k + 1u) * FCAP) epack[addr] = stage[p];
        }
    }
    // sentinel-fill the pad of each cell (no sync needed: disjoint regions)
    for (int i = t; i < NB; i += BSE) {
        unsigned s = gbase[i] + cnt[i];
        unsigned e = gbase[i] + ((cnt[i] + 15u) & ~15u);
        unsigned kend = ((unsigned)i + 1u) * FCAP;
        if (e > kend) e = kend;
        for (unsigned p = s; p < e; ++p) epack[p] = NOEDGE;
    }
}

// P2: per bucket — stage slab straight into registers (static unroll: VGPRs,
// no scratch), count per node, wave-shuffle scan, counting sort into LDS,
// coalesced writeback. Emits meta = excl|(c<<14), x_scaled.
__global__ void k_build(unsigned* __restrict__ epack, const unsigned* __restrict__ gcur,
                        const float* __restrict__ x,
                        unsigned* __restrict__ meta,
                        float* __restrict__ x_scaled, int N) {
    __shared__ unsigned stage[FCAP];     // sorted src lists only
    __shared__ unsigned cnt[BSB];
    __shared__ unsigned cur[BSB];
    __shared__ unsigned wsum[BSB / 64];
    __shared__ unsigned s_lenv;
    const int k = blockIdx.x, t = threadIdx.x;     // 512 threads
    const unsigned base = (unsigned)k * FCAP;
    const int len = min((int)gcur[k], FCAP);       // includes sentinel pad
    unsigned r[RSTG];                              // static unroll -> VGPRs
    #pragma unroll
    for (int j = 0; j < RSTG; ++j) {
        int i = t + j * BSB;                       // coalesced 4B loads
        r[j] = (i < len) ? epack[base + i] : NOEDGE;
    }
    cnt[t] = 0;
    __syncthreads();
    #pragma unroll
    for (int j = 0; j < RSTG; ++j) {
        unsigned p = r[j];
        if (p != NOEDGE) atomicAdd(&cnt[p & (NBW - 1u)], 1u);
    }
    __syncthreads();
    const unsigned c = cnt[t];
    unsigned v = c;                                // inclusive wave-scan (64)
    #pragma unroll
    for (int off = 1; off < 64; off <<= 1) {
        unsigned u = __shfl_up(v, off);
        if ((t & 63) >= off) v += u;
    }
    if ((t & 63) == 63) wsum[t >> 6] = v;
    __syncthreads();
    if (t < BSB / 64) {                            // scan the 8 wave sums
        unsigned w = wsum[t];
        #pragma unroll
        for (int off = 1; off < BSB / 64; off <<= 1) {
            unsigned u = __shfl_up(w, off);
            if (t >= off) w += u;
        }
        wsum[t] = w;                               // inclusive
    }
    __syncthreads();
    const unsigned incl = v + ((t >> 6) ? wsum[(t >> 6) - 1] : 0u);
    const unsigned excl = incl - c;
    cur[t] = excl;
    if (t == BSB - 1) s_lenv = incl;               // valid edge count
    const int node = k * NBW + t;
    if (node < N) {
        meta[node] = excl | (c << 14);             // both < 2^14
        float di = rsqrtf((float)(c + 1u));        // +1: self loop
        float4 xv = ((const float4*)x)[node];
        ((float4*)x_scaled)[node] = make_float4(xv.x * di, xv.y * di, xv.z * di, xv.w * di);
    }
    __syncthreads();
    #pragma unroll
    for (int j = 0; j < RSTG; ++j) {
        unsigned p = r[j];
        if (p != NOEDGE) {
            unsigned pos = atomicAdd(&cur[p & (NBW - 1u)], 1u);
            stage[pos] = p >> SH;                  // sorted src lists
        }
    }
    __syncthreads();
    const int lenv = (int)s_lenv;
    for (int i = 4 * t; i + 3 < lenv; i += 4 * BSB)  // coalesced writeback
        *(int4*)(epack + base + i) = *(const int4*)&stage[i];
    if (t < (lenv & 3)) epack[base + (lenv & ~3) + t] = stage[(lenv & ~3) + t];
}

// P3: pull-mode layer-1 aggregation + fused node math (no atomics).
__global__ void k_agg1(const unsigned* __restrict__ esorted, const unsigned* __restrict__ meta,
                       const float* __restrict__ x_scaled,
                       const float* __restrict__ W1, const float* __restrict__ b1,
                       const float* __restrict__ W2,
                       float* __restrict__ z_scaled, int N) {
    int node = blockIdx.x * blockDim.x + threadIdx.x;
    if (node >= N) return;
    unsigned m = meta[node];
    unsigned c = m >> 14;
    unsigned lo = (unsigned)(node >> SH) * FCAP + (m & 16383u);
    unsigned hi = lo + c;
    float di = rsqrtf((float)(c + 1u));
    const float4* xs4 = (const float4*)x_scaled;
    float4 a0 = xs4[node];                          // self loop
    float4 a1 = make_float4(0.f, 0.f, 0.f, 0.f);
    float4 a2 = make_float4(0.f, 0.f, 0.f, 0.f);
    float4 a3 = make_float4(0.f, 0.f, 0.f, 0.f);
    unsigned i = lo;
    for (; i + 3 < hi; i += 4) {                    // 4 gathers in flight
        float4 v0 = xs4[esorted[i]],     v1 = xs4[esorted[i + 1]];
        float4 v2 = xs4[esorted[i + 2]], v3 = xs4[esorted[i + 3]];
        a0.x += v0.x; a0.y += v0.y; a0.z += v0.z; a0.w += v0.w;
        a1.x += v1.x; a1.y += v1.y; a1.z += v1.z; a1.w += v1.w;
        a2.x += v2.x; a2.y += v2.y; a2.z += v2.z; a2.w += v2.w;
        a3.x += v3.x; a3.y += v3.y; a3.z += v3.z; a3.w += v3.w;
    }
    for (; i < hi; ++i) {
        float4 v = xs4[esorted[i]];
        a0.x += v.x; a0.y += v.y; a0.z += v.z; a0.w += v.w;
    }
    float p0 = di * (a0.x + a1.x + a2.x + a3.x);
    float p1 = di * (a0.y + a1.y + a2.y + a3.y);
    float p2 = di * (a0.z + a1.z + a2.z + a3.z);
    float p3 = di * (a0.w + a1.w + a2.w + a3.w);
    float z = 0.0f;
    #pragma unroll
    for (int cc = 0; cc < 16; ++cc) {
        float h1 = p0 * W1[0 * 16 + cc] + p1 * W1[1 * 16 + cc]
                 + p2 * W1[2 * 16 + cc] + p3 * W1[3 * 16 + cc] + b1[cc];
        h1 = fmaxf(h1, 0.0f);
        z += h1 * W2[cc];
    }
    z_scaled[node] = z * di;
}

// P4: pull-mode layer-2 aggregation (no atomics).
__global__ void k_agg2(const unsigned* __restrict__ esorted, const unsigned* __restrict__ meta,
                       const float* __restrict__ z_scaled,
                       const float* __restrict__ b2, float* __restrict__ out, int N) {
    int node = blockIdx.x * blockDim.x + threadIdx.x;
    if (node >= N) return;
    unsigned m = meta[node];
    unsigned c = m >> 14;
    unsigned lo = (unsigned)(node >> SH) * FCAP + (m & 16383u);
    unsigned hi = lo + c;
    float di = rsqrtf((float)(c + 1u));
    float a0 = z_scaled[node], a1 = 0.f, a2 = 0.f, a3 = 0.f;  // self loop in a0
    unsigned i = lo;
    for (; i + 3 < hi; i += 4) {
        a0 += z_scaled[esorted[i]];
        a1 += z_scaled[esorted[i + 1]];
        a2 += z_scaled[esorted[i + 2]];
        a3 += z_scaled[esorted[i + 3]];
    }
    for (; i < hi; ++i) a0 += z_scaled[esorted[i]];
    out[node] = di * (a0 + a1 + a2 + a3) + b2[0];
}

extern "C" void kernel_launch(void* const* d_in, const int* in_sizes, int n_in,
                              void* d_out, int out_size, void* d_ws, size_t ws_size,
                              hipStream_t stream) {
    const float* x  = (const float*)d_in[0];
    const int*   ei = (const int*)d_in[1];   // [2, E] as int32
    const float* W1 = (const float*)d_in[2];
    const float* b1 = (const float*)d_in[3];
    const float* W2 = (const float*)d_in[4];
    const float* b2 = (const float*)d_in[5];

    const int N = in_sizes[0] / 4;
    const int E = in_sizes[1] / 2;
    const int* src = ei;
    const int* dst = ei + E;
    const int NA = (E + CH - 1) / CH;        // 196

    // Workspace (~19 MB): gcur | epack[NB*FCAP] | meta[N] | x_scaled[N*4] |
    //   z_scaled[N]
    char* ws = (char*)d_ws;
    unsigned* gcur     = (unsigned*)ws;  ws += 4096;
    unsigned* epack    = (unsigned*)ws;  ws += (size_t)NB * FCAP * 4;
    unsigned* meta     = (unsigned*)ws;  ws += (size_t)N * 4;
    float*    x_scaled = (float*)ws;     ws += (size_t)N * 4 * 4;
    float*    z_scaled = (float*)ws;     ws += (size_t)N * 4;
    float* out = (float*)d_out;

    hipMemsetAsync(gcur, 0, NB * sizeof(unsigned), stream);
    k_bin  <<<NA, BSE, 0, stream>>>(src, dst, E, gcur, epack);
    k_build<<<NB, BSB, 0, stream>>>(epack, gcur, x, meta, x_scaled, N);
    k_agg1 <<<(N + 255) / 256, 256, 0, stream>>>(epack, meta, x_scaled,
                                                 W1, b1, W2, z_scaled, N);
    k_agg2 <<<(N + 255) / 256, 256, 0, stream>>>(epack, meta, z_scaled, b2, out, N);
}